// Round 1
// baseline (843.029 us; speedup 1.0000x reference)
//
#include <hip/hip_runtime.h>

// MaxUnpooling2D scatter-add.
// updates: (16,64,64,256) f32, mask: same shape i32 with flattened NHWC index
// m = (y*Wo + x)*C + f  (Wo=128, C=256 -> m = y<<15 | x<<8 | f).
// Reference ignores decoded f; destination channel = input channel c.
// out[b<<22 | (m & ~255) | c] += updates[i], duplicates summed.

constexpr int NIN = 16 * 64 * 64 * 256;      // 16,777,216 input elements
constexpr int NVEC = NIN / 4;                // 4,194,304 float4/int4 vectors

__global__ __launch_bounds__(256) void unpool_scatter(
    const float4* __restrict__ upd,
    const int4*  __restrict__ msk,
    float* __restrict__ out)
{
    int t = blockIdx.x * 256 + threadIdx.x;      // vector index < 2^22
    int e = t << 2;                              // element index < 2^24
    float4 u = upd[t];
    int4  m = msk[t];
    int b = e >> 20;                             // per-batch elems = 2^20
    int c = e & 255;                             // channel of elem 0 (C=256 | 4)
    float* ob = out + ((long long)b << 22);      // per-batch out slab = 2^22
    atomicAdd(ob + ((m.x & ~255) | (c    )), u.x);
    atomicAdd(ob + ((m.y & ~255) | (c + 1)), u.y);
    atomicAdd(ob + ((m.z & ~255) | (c + 2)), u.z);
    atomicAdd(ob + ((m.w & ~255) | (c + 3)), u.w);
}

extern "C" void kernel_launch(void* const* d_in, const int* in_sizes, int n_in,
                              void* d_out, int out_size, void* d_ws, size_t ws_size,
                              hipStream_t stream) {
    const float4* upd = (const float4*)d_in[0];
    const int4*   msk = (const int4*)d_in[1];
    float* out = (float*)d_out;

    // Output must be zeroed every call (harness poisons once, never re-poisons).
    hipMemsetAsync(out, 0, (size_t)out_size * sizeof(float), stream);

    unpool_scatter<<<NVEC / 256, 256, 0, stream>>>(upd, msk, out);
}

// Round 3
// 840.003 us; speedup vs baseline: 1.0036x; 1.0036x over previous
//
#include <hip/hip_runtime.h>

// MaxUnpooling2D scatter-add, round 2b: ILP to fill the atomic pipe.
// dest = b<<22 | (m & ~255) | c  (Wo=128, C=256; reference discards decoded f).
// Each thread processes IPT=8 vec4 pairs, fully unrolled -> ~48 VMEM ops in
// flight per wave instead of 6. Nontemporal input loads keep the streaming
// reads from evicting output lines (output 268MB vs 256MB L3).

typedef float __attribute__((ext_vector_type(4))) f32x4;
typedef int   __attribute__((ext_vector_type(4))) i32x4;

constexpr int NIN   = 16 * 64 * 64 * 256;   // 16,777,216 elements
constexpr int NVEC  = NIN / 4;              // 4,194,304 vec4s
constexpr int IPT   = 8;                    // vec4s per thread
constexpr int TPB   = 256;
constexpr int STRIDE = NVEC / IPT;          // 524,288 vec4s per slice
constexpr int NBLK  = STRIDE / TPB;         // 2048 blocks

__global__ __launch_bounds__(TPB) void unpool_scatter(
    const f32x4* __restrict__ upd,
    const i32x4* __restrict__ msk,
    float* __restrict__ out)
{
    const int t0 = blockIdx.x * TPB + threadIdx.x;   // [0, STRIDE)
#pragma unroll
    for (int k = 0; k < IPT; ++k) {
        const int t = t0 + k * STRIDE;               // vec index < 2^22
        f32x4 u = __builtin_nontemporal_load(&upd[t]);
        i32x4 m = __builtin_nontemporal_load(&msk[t]);
        const int e = t << 2;                        // element index
        const int b = e >> 20;                       // 2^20 elems per batch
        const int c = e & 255;                       // channel of elem 0
        float* ob = out + ((long long)b << 22);      // 2^22 floats per out-batch
        atomicAdd(ob + ((m.x & ~255) | (c    )), u.x);
        atomicAdd(ob + ((m.y & ~255) | (c + 1)), u.y);
        atomicAdd(ob + ((m.z & ~255) | (c + 2)), u.z);
        atomicAdd(ob + ((m.w & ~255) | (c + 3)), u.w);
    }
}

extern "C" void kernel_launch(void* const* d_in, const int* in_sizes, int n_in,
                              void* d_out, int out_size, void* d_ws, size_t ws_size,
                              hipStream_t stream) {
    const f32x4* upd = (const f32x4*)d_in[0];
    const i32x4* msk = (const i32x4*)d_in[1];
    float* out = (float*)d_out;

    (void)hipMemsetAsync(out, 0, (size_t)out_size * sizeof(float), stream);
    unpool_scatter<<<NBLK, TPB, 0, stream>>>(upd, msk, out);
}